// Round 1
// baseline (745.185 us; speedup 1.0000x reference)
//
#include <hip/hip_runtime.h>
#include <math.h>

#define N_NODES 8192
#define IN_DIM  512
#define H_DIM   128

__device__ __forceinline__ float lrelu(float x) { return x >= 0.f ? x : 0.2f * x; }

// monotonic float<->uint mapping for atomicMax on floats
__device__ __forceinline__ unsigned int f2mono(float x) {
    unsigned int b = __float_as_uint(x);
    return (b & 0x80000000u) ? ~b : (b | 0x80000000u);
}
__device__ __forceinline__ float mono2f(unsigned int u) {
    unsigned int b = (u & 0x80000000u) ? (u ^ 0x80000000u) : ~u;
    return __uint_as_float(b);
}

__global__ void k_init(unsigned int* smax) {
    if (threadIdx.x == 0) *smax = 0u;  // below every finite mapped float
}

// Wh = h @ W_w^T + W_b   (8192x128, f32)
__global__ __launch_bounds__(256) void k_wh(const float* __restrict__ h,
                                            const float* __restrict__ Ww,
                                            const float* __restrict__ Wb,
                                            float* __restrict__ Wh) {
    const int BM = 32, BK = 64;
    __shared__ float hT[BK][BM + 4];      // [k][r], stride 36 (144B, 16B-aligned rows)
    __shared__ float wT[BK][H_DIM + 4];   // [k][c], stride 132 (528B)
    const int tid = threadIdx.x;
    const int w = tid >> 6, lane = tid & 63;
    const int trm = tid >> 5, tcm = tid & 31;
    const int row0 = blockIdx.x * BM;

    float acc[4][4] = {};
    for (int k0 = 0; k0 < IN_DIM; k0 += BK) {
        __syncthreads();
        #pragma unroll
        for (int p = 0; p < 8; ++p) {
            int r = 4 * p + w;
            hT[lane][r] = h[(size_t)(row0 + r) * IN_DIM + k0 + lane];
        }
        #pragma unroll
        for (int p = 0; p < 32; ++p) {
            int c = 4 * p + w;
            wT[lane][c] = Ww[(size_t)c * IN_DIM + k0 + lane];
        }
        __syncthreads();
        #pragma unroll 8
        for (int kk = 0; kk < BK; ++kk) {
            float4 a4 = *(const float4*)&hT[kk][4 * trm];
            float4 b4 = *(const float4*)&wT[kk][4 * tcm];
            float av[4] = {a4.x, a4.y, a4.z, a4.w};
            float bv[4] = {b4.x, b4.y, b4.z, b4.w};
            #pragma unroll
            for (int i = 0; i < 4; ++i)
                #pragma unroll
                for (int j = 0; j < 4; ++j)
                    acc[i][j] = fmaf(av[i], bv[j], acc[i][j]);
        }
    }
    float4 wb4 = *(const float4*)&Wb[4 * tcm];
    #pragma unroll
    for (int i = 0; i < 4; ++i) {
        float4 o = make_float4(acc[i][0] + wb4.x, acc[i][1] + wb4.y,
                               acc[i][2] + wb4.z, acc[i][3] + wb4.w);
        *(float4*)&Wh[(size_t)(row0 + 4 * trm + i) * H_DIM + 4 * tcm] = o;
    }
}

// s_i = Wh_i . a ; also global max(s) via mapped atomicMax
__global__ __launch_bounds__(256) void k_s(const float* __restrict__ Wh,
                                           const float* __restrict__ a,
                                           float* __restrict__ s,
                                           unsigned int* __restrict__ smax) {
    const int w = threadIdx.x >> 6, lane = threadIdx.x & 63;
    const int row = blockIdx.x * 4 + w;
    float2 av = *(const float2*)&a[lane * 2];
    float2 wh = *(const float2*)&Wh[(size_t)row * H_DIM + lane * 2];
    float v = wh.x * av.x + wh.y * av.y;
    #pragma unroll
    for (int off = 32; off > 0; off >>= 1) v += __shfl_down(v, off);
    __shared__ float bmax[4];
    if (lane == 0) { s[row] = v; bmax[w] = v; }
    __syncthreads();
    if (threadIdx.x == 0) {
        float m = fmaxf(fmaxf(bmax[0], bmax[1]), fmaxf(bmax[2], bmax[3]));
        atomicMax(smax, f2mono(m));
    }
}

// One streaming pass over adj: denom_i, y_i = sum_j ex_ij*Wh_j, and bitmask.
// ex_ij = adj? exp(lrelu(s_i+s_j) - m_i) : 0,  m_i = lrelu(s_i + S_max) >= masked max.
__global__ __launch_bounds__(256) void k_A(const float* __restrict__ adj,
                                           const float* __restrict__ Wh,
                                           const float* __restrict__ s,
                                           const unsigned int* __restrict__ smaxp,
                                           float* __restrict__ denom,
                                           float* __restrict__ y,
                                           unsigned long long* __restrict__ bmask,
                                           int write_mask) {
    const int BM = 32, BJ = 64, NT = N_NODES / BJ;
    __shared__ float exT[BJ][BM + 4];    // [j][r], stride 36
    __shared__ float whs[BJ][H_DIM];     // [j][c]
    const int tid = threadIdx.x;
    const int w = tid >> 6, lane = tid & 63;
    const int trm = tid >> 5, tcm = tid & 31;
    const int row0 = blockIdx.x * BM;
    const float smax = mono2f(*smaxp);

    float si[8], mi[8], dsum[8];
    #pragma unroll
    for (int p = 0; p < 8; ++p) {
        si[p] = s[row0 + 4 * p + w];
        mi[p] = lrelu(si[p] + smax);
        dsum[p] = 0.f;
    }

    float acc[4][4] = {};
    float adjreg[8];
    float4 whreg[8];
    float sjreg;

    // prefetch tile 0
    {
        const float* ap = adj + (size_t)row0 * N_NODES + lane;
        #pragma unroll
        for (int p = 0; p < 8; ++p) adjreg[p] = ap[(size_t)(4 * p + w) * N_NODES];
        #pragma unroll
        for (int p = 0; p < 8; ++p) {
            int idx = p * 256 + tid;
            whreg[p] = *(const float4*)&Wh[(size_t)(idx >> 5) * H_DIM + 4 * (idx & 31)];
        }
        sjreg = s[lane];
    }

    for (int t = 0; t < NT; ++t) {
        float exv[8];
        #pragma unroll
        for (int p = 0; p < 8; ++p) {
            bool nb = (adjreg[p] != 0.f);
            float e = lrelu(si[p] + sjreg) - mi[p];
            float ex = nb ? __expf(e) : 0.f;
            exv[p] = ex;
            dsum[p] += ex;
            unsigned long long bal = __ballot(nb);
            if (write_mask && lane == 0)
                bmask[(size_t)(row0 + 4 * p + w) * NT + t] = bal;
        }
        __syncthreads();   // previous matmul done, LDS free
        #pragma unroll
        for (int p = 0; p < 8; ++p) exT[lane][4 * p + w] = exv[p];
        #pragma unroll
        for (int p = 0; p < 8; ++p) {
            int idx = p * 256 + tid;
            *(float4*)&whs[idx >> 5][4 * (idx & 31)] = whreg[p];
        }
        __syncthreads();
        // prefetch next tile: issued here so HBM latency hides under the matmul
        if (t + 1 < NT) {
            int j0 = (t + 1) * BJ;
            const float* ap = adj + (size_t)row0 * N_NODES + j0 + lane;
            #pragma unroll
            for (int p = 0; p < 8; ++p) adjreg[p] = ap[(size_t)(4 * p + w) * N_NODES];
            #pragma unroll
            for (int p = 0; p < 8; ++p) {
                int idx = p * 256 + tid;
                whreg[p] = *(const float4*)&Wh[(size_t)(j0 + (idx >> 5)) * H_DIM + 4 * (idx & 31)];
            }
            sjreg = s[j0 + lane];
        }
        #pragma unroll 8
        for (int j = 0; j < BJ; ++j) {
            float4 a4 = *(const float4*)&exT[j][4 * trm];
            float4 b4 = *(const float4*)&whs[j][4 * tcm];
            float av[4] = {a4.x, a4.y, a4.z, a4.w};
            float bv[4] = {b4.x, b4.y, b4.z, b4.w};
            #pragma unroll
            for (int i = 0; i < 4; ++i)
                #pragma unroll
                for (int jj = 0; jj < 4; ++jj)
                    acc[i][jj] = fmaf(av[i], bv[jj], acc[i][jj]);
        }
    }

    #pragma unroll
    for (int p = 0; p < 8; ++p) {
        float v = dsum[p];
        #pragma unroll
        for (int off = 32; off > 0; off >>= 1) v += __shfl_down(v, off);
        if (lane == 0) denom[row0 + 4 * p + w] = v;
    }
    #pragma unroll
    for (int i = 0; i < 4; ++i) {
        float4 o = make_float4(acc[i][0], acc[i][1], acc[i][2], acc[i][3]);
        *(float4*)&y[(size_t)(row0 + 4 * trm + i) * H_DIM + 4 * tcm] = o;
    }
}

// alpha_ij = ex_ij / denom_i ; reads 8MB bitmask (or adj fallback), writes 268MB
__global__ __launch_bounds__(256) void k_B(const unsigned long long* __restrict__ bmask,
                                           const float* __restrict__ adj,
                                           const float* __restrict__ s,
                                           const float* __restrict__ denom,
                                           const unsigned int* __restrict__ smaxp,
                                           float* __restrict__ alpha,
                                           int use_mask) {
    const int NT = N_NODES / 64;
    const int w = threadIdx.x >> 6, lane = threadIdx.x & 63;
    const int row = blockIdx.x * 4 + w;
    const float smax = mono2f(*smaxp);
    const float si = s[row];
    const float mi = lrelu(si + smax);
    const float d = denom[row];
    const float rd = d > 0.f ? 1.f / d : 0.f;
    float* arow = alpha + (size_t)row * N_NODES;
    if (use_mask) {
        const unsigned long long* mrow = bmask + (size_t)row * NT;
        #pragma unroll 4
        for (int t = 0; t < NT; ++t) {
            unsigned long long mb = mrow[t];
            bool nb = (mb >> lane) & 1ull;
            float sj = s[t * 64 + lane];
            float ex = nb ? __expf(lrelu(si + sj) - mi) : 0.f;
            arow[t * 64 + lane] = ex * rd;
        }
    } else {
        const float* adjrow = adj + (size_t)row * N_NODES;
        #pragma unroll 4
        for (int t = 0; t < NT; ++t) {
            bool nb = adjrow[t * 64 + lane] != 0.f;
            float sj = s[t * 64 + lane];
            float ex = nb ? __expf(lrelu(si + sj) - mi) : 0.f;
            arow[t * 64 + lane] = ex * rd;
        }
    }
}

// z = sigmoid(y/denom)
__global__ __launch_bounds__(256) void k_z(const float* __restrict__ y,
                                           const float* __restrict__ denom,
                                           float* __restrict__ z) {
    int i = blockIdx.x * 256 + threadIdx.x;
    int row = i >> 7;
    float d = denom[row];
    float rd = d > 0.f ? 1.f / d : 0.f;
    float v = y[i] * rd;
    z[i] = 1.f / (1.f + __expf(-v));
}

extern "C" void kernel_launch(void* const* d_in, const int* in_sizes, int n_in,
                              void* d_out, int out_size, void* d_ws, size_t ws_size,
                              hipStream_t stream) {
    const float* h   = (const float*)d_in[0];
    const float* adj = (const float*)d_in[1];
    const float* Ww  = (const float*)d_in[2];
    const float* Wb  = (const float*)d_in[3];
    const float* a   = (const float*)d_in[4];

    float* z     = (float*)d_out;
    float* alpha = z + (size_t)N_NODES * H_DIM;

    char* ws = (char*)d_ws;
    float* Wh    = (float*)ws;  ws += sizeof(float) * (size_t)N_NODES * H_DIM;
    float* y     = (float*)ws;  ws += sizeof(float) * (size_t)N_NODES * H_DIM;
    float* s     = (float*)ws;  ws += sizeof(float) * N_NODES;
    float* denom = (float*)ws;  ws += sizeof(float) * N_NODES;
    unsigned int* smax = (unsigned int*)ws;  ws += 256;
    unsigned long long* bmask = (unsigned long long*)ws;
    size_t base_need  = (size_t)(ws - (char*)d_ws);
    size_t mask_bytes = (size_t)N_NODES * (N_NODES / 64) * sizeof(unsigned long long);
    int use_mask = (ws_size >= base_need + mask_bytes) ? 1 : 0;

    hipLaunchKernelGGL(k_init, dim3(1), dim3(64), 0, stream, smax);
    hipLaunchKernelGGL(k_wh,   dim3(N_NODES / 32), dim3(256), 0, stream, h, Ww, Wb, Wh);
    hipLaunchKernelGGL(k_s,    dim3(N_NODES / 4),  dim3(256), 0, stream, Wh, a, s, smax);
    hipLaunchKernelGGL(k_A,    dim3(N_NODES / 32), dim3(256), 0, stream,
                       adj, Wh, s, smax, denom, y, bmask, use_mask);
    hipLaunchKernelGGL(k_B,    dim3(N_NODES / 4),  dim3(256), 0, stream,
                       bmask, adj, s, denom, smax, alpha, use_mask);
    hipLaunchKernelGGL(k_z,    dim3((N_NODES * H_DIM) / 256), dim3(256), 0, stream,
                       y, denom, z);
}

// Round 2
// 387.453 us; speedup vs baseline: 1.9233x; 1.9233x over previous
//
#include <hip/hip_runtime.h>
#include <hip/hip_bf16.h>
#include <math.h>

#define N_NODES 8192
#define IN_DIM  512
#define H_DIM   128
#define KC      4096              // K-chunk per k-block in k_A
#define NKB     (N_NODES / KC)    // 2

typedef __attribute__((ext_vector_type(8))) short bf16x8;
typedef __attribute__((ext_vector_type(4))) float f32x4;

__device__ __forceinline__ float lrelu(float x) { return fmaxf(x, 0.2f * x); }

// monotonic float<->uint mapping for atomicMax on floats (all finite maps > 0)
__device__ __forceinline__ unsigned int f2mono(float x) {
    unsigned int b = __float_as_uint(x);
    return (b & 0x80000000u) ? ~b : (b | 0x80000000u);
}
__device__ __forceinline__ float mono2f(unsigned int u) {
    unsigned int b = (u & 0x80000000u) ? (u ^ 0x80000000u) : ~u;
    return __uint_as_float(b);
}

__device__ __forceinline__ short f2bf(float x) {
    union { __hip_bfloat16 h; short s; } cv;
    cv.h = __float2bfloat16(x);
    return cv.s;
}

// Wh = h @ W_w^T + W_b (f32) ; also WhT = bf16 transpose [H_DIM][N_NODES]
__global__ __launch_bounds__(256) void k_wh(const float* __restrict__ h,
                                            const float* __restrict__ Ww,
                                            const float* __restrict__ Wb,
                                            float* __restrict__ Wh,
                                            __hip_bfloat16* __restrict__ WhT) {
    const int BM = 32, BK = 64;
    __shared__ float hT[BK][BM + 4];
    __shared__ float wT[BK][H_DIM + 4];
    const int tid = threadIdx.x;
    const int w = tid >> 6, lane = tid & 63;
    const int trm = tid >> 5, tcm = tid & 31;
    const int row0 = blockIdx.x * BM;

    float acc[4][4] = {};
    for (int k0 = 0; k0 < IN_DIM; k0 += BK) {
        __syncthreads();
        #pragma unroll
        for (int p = 0; p < 8; ++p) {
            int r = 4 * p + w;
            hT[lane][r] = h[(size_t)(row0 + r) * IN_DIM + k0 + lane];
        }
        #pragma unroll
        for (int p = 0; p < 32; ++p) {
            int c = 4 * p + w;
            wT[lane][c] = Ww[(size_t)c * IN_DIM + k0 + lane];
        }
        __syncthreads();
        #pragma unroll 8
        for (int kk = 0; kk < BK; ++kk) {
            float4 a4 = *(const float4*)&hT[kk][4 * trm];
            float4 b4 = *(const float4*)&wT[kk][4 * tcm];
            float av[4] = {a4.x, a4.y, a4.z, a4.w};
            float bv[4] = {b4.x, b4.y, b4.z, b4.w};
            #pragma unroll
            for (int i = 0; i < 4; ++i)
                #pragma unroll
                for (int j = 0; j < 4; ++j)
                    acc[i][j] = fmaf(av[i], bv[j], acc[i][j]);
        }
    }
    float4 wb4 = *(const float4*)&Wb[4 * tcm];
    #pragma unroll
    for (int i = 0; i < 4; ++i) {
        int row = row0 + 4 * trm + i;
        float v[4] = {acc[i][0] + wb4.x, acc[i][1] + wb4.y,
                      acc[i][2] + wb4.z, acc[i][3] + wb4.w};
        *(float4*)&Wh[(size_t)row * H_DIM + 4 * tcm] = make_float4(v[0], v[1], v[2], v[3]);
        #pragma unroll
        for (int jj = 0; jj < 4; ++jj)
            WhT[(size_t)(4 * tcm + jj) * N_NODES + row] = __float2bfloat16(v[jj]);
    }
}

// s_i = Wh_i . a ; global max(s) via mapped atomicMax
__global__ __launch_bounds__(256) void k_s(const float* __restrict__ Wh,
                                           const float* __restrict__ a,
                                           float* __restrict__ s,
                                           unsigned int* __restrict__ smax) {
    const int w = threadIdx.x >> 6, lane = threadIdx.x & 63;
    const int row = blockIdx.x * 4 + w;
    float2 av = *(const float2*)&a[lane * 2];
    float2 wh = *(const float2*)&Wh[(size_t)row * H_DIM + lane * 2];
    float v = wh.x * av.x + wh.y * av.y;
    #pragma unroll
    for (int off = 32; off > 0; off >>= 1) v += __shfl_down(v, off);
    __shared__ float bmax[4];
    if (lane == 0) { s[row] = v; bmax[w] = v; }
    __syncthreads();
    if (threadIdx.x == 0) {
        float m = fmaxf(fmaxf(bmax[0], bmax[1]), fmaxf(bmax[2], bmax[3]));
        atomicMax(smax, f2mono(m));
    }
}

// Streaming MFMA pass over adj: y += EX_chunk @ Whb, denom += rowsum(EX), bitmask.
// Barrier-free, LDS-free. 8 waves: (w&3)=row-group of 16 rows, (w>>2)=col half of 64.
__global__ __launch_bounds__(512) void k_A(const float* __restrict__ adj,
                                           const __hip_bfloat16* __restrict__ WhT,
                                           const float* __restrict__ s,
                                           const unsigned int* __restrict__ smaxp,
                                           float* __restrict__ denom,
                                           float* __restrict__ y,
                                           unsigned long long* __restrict__ bmask,
                                           int write_mask) {
    const int NTW = N_NODES / 64;  // bmask words per row
    const int tid  = threadIdx.x;
    const int lane = tid & 63;
    const int w    = tid >> 6;
    const int rg   = w & 3;        // row-group
    const int cg   = w >> 2;       // col half
    const int r    = lane & 15;
    const int kq   = lane >> 4;    // k-quarter: k = kq*8 + e
    const int row0 = blockIdx.x * 64;
    const int j0base = blockIdx.y * KC;
    const int rowA = row0 + rg * 16 + r;

    const float smax = mono2f(*smaxp);
    const float si = s[rowA];
    const float mi = lrelu(si + smax);

    f32x4 acc[4] = {{0.f,0.f,0.f,0.f},{0.f,0.f,0.f,0.f},{0.f,0.f,0.f,0.f},{0.f,0.f,0.f,0.f}};
    float dsum = 0.f;

    const float* ap = adj + (size_t)rowA * N_NODES + j0base + kq * 8;
    const float* sp = s + j0base + kq * 8;
    const __hip_bfloat16* bp = WhT + (size_t)(cg * 64 + r) * N_NODES + j0base + kq * 8;

    const int NSTEP = KC / 32;  // 128

    float4 ac0 = *(const float4*)(ap);
    float4 ac1 = *(const float4*)(ap + 4);
    float4 sc0 = *(const float4*)(sp);
    float4 sc1 = *(const float4*)(sp + 4);
    bf16x8 bc[4];
    #pragma unroll
    for (int f = 0; f < 4; ++f) bc[f] = *(const bf16x8*)(bp + (size_t)f * 16 * N_NODES);

    unsigned long long pend = 0ull;

    #pragma unroll 2
    for (int t = 0; t < NSTEP; ++t) {
        // prefetch next k-step (uniform branch)
        float4 an0, an1, sn0, sn1; bf16x8 bn[4];
        if (t + 1 < NSTEP) {
            const float* ap2 = ap + (size_t)(t + 1) * 32;
            an0 = *(const float4*)(ap2);
            an1 = *(const float4*)(ap2 + 4);
            const float* sp2 = sp + (t + 1) * 32;
            sn0 = *(const float4*)(sp2);
            sn1 = *(const float4*)(sp2 + 4);
            const __hip_bfloat16* bp2 = bp + (t + 1) * 32;
            #pragma unroll
            for (int f = 0; f < 4; ++f) bn[f] = *(const bf16x8*)(bp2 + (size_t)f * 16 * N_NODES);
        }
        // ex for this lane's 8 (row, j) elements, packed into MFMA A-fragment
        float av[8] = {ac0.x, ac0.y, ac0.z, ac0.w, ac1.x, ac1.y, ac1.z, ac1.w};
        float sv[8] = {sc0.x, sc0.y, sc0.z, sc0.w, sc1.x, sc1.y, sc1.z, sc1.w};
        bf16x8 afrag;
        unsigned int bits = 0u;
        #pragma unroll
        for (int e = 0; e < 8; ++e) {
            bool nb = (av[e] != 0.f);
            float ex = nb ? __expf(lrelu(si + sv[e]) - mi) : 0.f;
            dsum += ex;
            bits |= nb ? (1u << e) : 0u;
            afrag[e] = f2bf(ex);
        }
        #pragma unroll
        for (int f = 0; f < 4; ++f)
            acc[f] = __builtin_amdgcn_mfma_f32_16x16x32_bf16(afrag, bc[f], acc[f], 0, 0, 0);
        // bitmask: 32 bits/step, combine 2 steps -> 64-bit word (col-half 0 only)
        if (write_mask && cg == 0) {
            unsigned long long w32 = (unsigned long long)bits << (8 * kq);
            if ((t & 1) == 0) {
                pend = w32;
            } else {
                unsigned long long full = pend | (w32 << 32);
                full |= __shfl_xor(full, 16);
                full |= __shfl_xor(full, 32);
                if (lane < 16)
                    bmask[(size_t)(row0 + rg * 16 + lane) * NTW + ((j0base + t * 32) >> 6)] = full;
            }
        }
        ac0 = an0; ac1 = an1; sc0 = sn0; sc1 = sn1;
        #pragma unroll
        for (int f = 0; f < 4; ++f) bc[f] = bn[f];
    }

    // denom partial: sum lanes with same r (kq=0..3), col-half 0 only
    if (cg == 0) {
        float v = dsum;
        v += __shfl_xor(v, 16);
        v += __shfl_xor(v, 32);
        if (lane < 16) atomicAdd(&denom[row0 + rg * 16 + lane], v);
    }
    // y partial: D layout col = c0 + (lane&15), row = (lane>>4)*4 + reg
    #pragma unroll
    for (int f = 0; f < 4; ++f)
        #pragma unroll
        for (int i = 0; i < 4; ++i) {
            int rr = row0 + rg * 16 + kq * 4 + i;
            int cc = cg * 64 + f * 16 + r;
            atomicAdd(&y[(size_t)rr * H_DIM + cc], acc[f][i]);
        }
}

// alpha_ij = ex_ij / denom_i ; reads 8MB bitmask (or adj fallback), writes 268MB
__global__ __launch_bounds__(256) void k_B(const unsigned long long* __restrict__ bmask,
                                           const float* __restrict__ adj,
                                           const float* __restrict__ s,
                                           const float* __restrict__ denom,
                                           const unsigned int* __restrict__ smaxp,
                                           float* __restrict__ alpha,
                                           int use_mask) {
    const int NT = N_NODES / 64;
    const int w = threadIdx.x >> 6, lane = threadIdx.x & 63;
    const int row = blockIdx.x * 4 + w;
    const float smax = mono2f(*smaxp);
    const float si = s[row];
    const float mi = lrelu(si + smax);
    const float d = denom[row];
    const float rd = d > 0.f ? 1.f / d : 0.f;
    float* arow = alpha + (size_t)row * N_NODES;
    if (use_mask) {
        const unsigned long long* mrow = bmask + (size_t)row * NT;
        #pragma unroll 4
        for (int t = 0; t < NT; ++t) {
            unsigned long long mb = mrow[t];
            bool nb = (mb >> lane) & 1ull;
            float sj = s[t * 64 + lane];
            float ex = nb ? __expf(lrelu(si + sj) - mi) : 0.f;
            arow[t * 64 + lane] = ex * rd;
        }
    } else {
        const float* adjrow = adj + (size_t)row * N_NODES;
        #pragma unroll 4
        for (int t = 0; t < NT; ++t) {
            bool nb = adjrow[t * 64 + lane] != 0.f;
            float sj = s[t * 64 + lane];
            float ex = nb ? __expf(lrelu(si + sj) - mi) : 0.f;
            arow[t * 64 + lane] = ex * rd;
        }
    }
}

// z = sigmoid(y/denom)
__global__ __launch_bounds__(256) void k_z(const float* __restrict__ y,
                                           const float* __restrict__ denom,
                                           float* __restrict__ z) {
    int i = blockIdx.x * 256 + threadIdx.x;
    int row = i >> 7;
    float d = denom[row];
    float rd = d > 0.f ? 1.f / d : 0.f;
    float v = y[i] * rd;
    z[i] = 1.f / (1.f + __expf(-v));
}

extern "C" void kernel_launch(void* const* d_in, const int* in_sizes, int n_in,
                              void* d_out, int out_size, void* d_ws, size_t ws_size,
                              hipStream_t stream) {
    const float* h   = (const float*)d_in[0];
    const float* adj = (const float*)d_in[1];
    const float* Ww  = (const float*)d_in[2];
    const float* Wb  = (const float*)d_in[3];
    const float* a   = (const float*)d_in[4];

    float* z     = (float*)d_out;
    float* alpha = z + (size_t)N_NODES * H_DIM;

    char* ws = (char*)d_ws;
    float* y     = (float*)ws;  ws += sizeof(float) * (size_t)N_NODES * H_DIM;   // 4MB (zeroed)
    float* denom = (float*)ws;  ws += sizeof(float) * N_NODES;                   // 32KB (zeroed)
    unsigned int* smax = (unsigned int*)ws;  ws += 256;                          // (zeroed)
    size_t zero_bytes = (size_t)(ws - (char*)d_ws);
    float* Wh    = (float*)ws;  ws += sizeof(float) * (size_t)N_NODES * H_DIM;   // 4MB
    __hip_bfloat16* WhT = (__hip_bfloat16*)ws;
    ws += sizeof(__hip_bfloat16) * (size_t)N_NODES * H_DIM;                      // 2MB
    float* s     = (float*)ws;  ws += sizeof(float) * N_NODES;                   // 32KB
    unsigned long long* bmask = (unsigned long long*)ws;
    size_t base_need  = (size_t)(ws - (char*)d_ws);
    size_t mask_bytes = (size_t)N_NODES * (N_NODES / 64) * sizeof(unsigned long long);
    int use_mask = (ws_size >= base_need + mask_bytes) ? 1 : 0;

    hipMemsetAsync(d_ws, 0, zero_bytes, stream);
    hipLaunchKernelGGL(k_wh, dim3(N_NODES / 32), dim3(256), 0, stream, h, Ww, Wb, Wh, WhT);
    hipLaunchKernelGGL(k_s,  dim3(N_NODES / 4),  dim3(256), 0, stream, Wh, a, s, smax);
    hipLaunchKernelGGL(k_A,  dim3(N_NODES / 64, NKB), dim3(512), 0, stream,
                       adj, WhT, s, smax, denom, y, bmask, use_mask);
    hipLaunchKernelGGL(k_B,  dim3(N_NODES / 4),  dim3(256), 0, stream,
                       bmask, adj, s, denom, smax, alpha, use_mask);
    hipLaunchKernelGGL(k_z,  dim3((N_NODES * H_DIM) / 256), dim3(256), 0, stream,
                       y, denom, z);
}